// Round 13
// baseline (222.319 us; speedup 1.0000x reference)
//
#include <hip/hip_runtime.h>

#define MEDNUM 50000
#define FEATDIM 128
#define NNZ 3200000
#define NBUCK 1563             // ceil(50000/32): buckets of 32 folded rows
#define SLAB 2304              // fixed slab per bucket (mean 2047, +5.7 sigma)
#define PART_BLOCKS 250
#define PART_E 12800           // edges per block (250*12800 = NNZ exact)
#define PART_T 1024            // threads per part block (4 waves/SIMD)
#define PART_K 12              // 12*1024 = 12288 full records per thread
#define PART_TAIL 512          // 12800 - 12288
#define CAP SLAB

// ws layout (4-byte words):
#define OFF_CUR    0           // global slab cursors [1563]
#define OFF_SCALE  1600        // per-row fp32 scale [50000]
#define OFF_QT     51600       // biased-u8 table, PERMUTED layout, u16[50000*64] = 6.4 MB
#define OFF_RECS   3251600     // u64[NBUCK*SLAB] = 28.8 MB

// qt row layout (128 B): byte position 8q+j (q=0..15, j=0..7) holds feature
// 2q + 32*(j>>1) + (j&1). After agg's xor-16/32 reduction, lane l owns
// features 2l, 2l+1 (elements j=2*qw, 2*qw+1), so the output store is a dense
// 64-lane 8B store (512 B fully-covered lines -> no sector-RMW amplification).

// ---------------------------------------------------------------------------
// 0) fp32 -> per-row-scaled BIASED uint8 table (q+128; decode in agg uses
//    v_cvt_f32_ubyteN + deferred -128*sum(v) correction). One wave per row;
//    lane quantizes feats 2*lane, 2*lane+1 and stores the packed u16 at the
//    PERMUTED index (lane&15)*4 + (lane>>4). Also inits slab cursors.
// ---------------------------------------------------------------------------
__global__ __launch_bounds__(256) void toint8_kernel(const float* __restrict__ mEmbed,
                                                     unsigned short* __restrict__ qt,
                                                     float* __restrict__ scales,
                                                     int* __restrict__ gcur) {
    int g = blockIdx.x * 256 + threadIdx.x;
    if (g < NBUCK) gcur[g] = g * SLAB;

    int row = blockIdx.x * 4 + (threadIdx.x >> 6);
    int lane = threadIdx.x & 63;
    if (row >= MEDNUM) return;
    float2 f = ((const float2*)(mEmbed + (long long)row * FEATDIM))[lane];
    float m = fmaxf(fabsf(f.x), fabsf(f.y));
    for (int o = 32; o > 0; o >>= 1) m = fmaxf(m, __shfl_xor(m, o, 64));
    float inv = (m > 0.f) ? 127.f / m : 0.f;
    float s   = (m > 0.f) ? m / 127.f : 0.f;
    int q0 = __float2int_rn(f.x * inv) + 128;   // 1..255 biased
    int q1 = __float2int_rn(f.y * inv) + 128;
    qt[(long long)row * 64 + ((lane & 15) * 4 + (lane >> 4))] =
        (unsigned short)((q0 & 0xff) | ((q1 & 0xff) << 8));
    if (lane == 0) scales[row] = s;
}

// ---------------------------------------------------------------------------
// 1) partition: block-level counting sort. 250 blocks x 1024 threads, 12800
//    edges/block as u64 records in REGISTERS (K=12 + 512-thread tail), LDS
//    histogram -> block scan -> one global atomic per bucket -> place into
//    sorted LDS (102 KB) -> position-ordered coalesced writeout (~8-rec runs).
//    Record u64: [63]=bkt bit10 (vp sign is always 0; cleared on writeout),
//    [62:32]=vp fp32 bits (sign 0), [31:22]=bkt low10, [21:16]=rib, [15:0]=col.
// ---------------------------------------------------------------------------
__global__ __launch_bounds__(PART_T, 4) void part_kernel(const float* __restrict__ vals,
                                                         const int* __restrict__ row_idx,
                                                         const int* __restrict__ col_idx,
                                                         const float* __restrict__ scales,
                                                         int* __restrict__ gcur,
                                                         unsigned long long* __restrict__ recs) {
    __shared__ unsigned long long lrec[PART_E];   // 102400 B
    __shared__ int lcnt[NBUCK];                   // counts -> cursors
    __shared__ int gstart[NBUCK];                 // global_base - local_excl per bucket
    __shared__ int wsum[16];

    int tid = threadIdx.x;
    int base = blockIdx.x * PART_E;

    for (int i = tid; i < NBUCK; i += PART_T) lcnt[i] = 0;
    __syncthreads();

    // ---- single input pass: build records in registers + LDS histogram ----
    unsigned long long rec[PART_K];
    unsigned long long rtail = 0;
    int have_tail = (tid < PART_TAIL);
    {
        int rr[PART_K], cc[PART_K];
        float vv[PART_K];
#pragma unroll
        for (int k = 0; k < PART_K; k++) {
            int e = base + k * PART_T + tid;
            rr[k] = __builtin_nontemporal_load(row_idx + e);
            cc[k] = __builtin_nontemporal_load(col_idx + e);
            vv[k] = __builtin_nontemporal_load(vals + e);
        }
        int rt = 0, ct = 0; float vt = 0.f;
        if (have_tail) {
            int e = base + PART_K * PART_T + tid;
            rt = __builtin_nontemporal_load(row_idx + e);
            ct = __builtin_nontemporal_load(col_idx + e);
            vt = __builtin_nontemporal_load(vals + e);
        }
        float ss[PART_K];
#pragma unroll
        for (int k = 0; k < PART_K; k++) {
            cc[k] = (cc[k] >= MEDNUM) ? cc[k] - MEDNUM : cc[k];
            ss[k] = scales[cc[k]];
        }
        float st = 0.f;
        if (have_tail) {
            ct = (ct >= MEDNUM) ? ct - MEDNUM : ct;
            st = scales[ct];
        }
#pragma unroll
        for (int k = 0; k < PART_K; k++) {
            int r = rr[k], half = 0;
            if (r >= MEDNUM) { r -= MEDNUM; half = 1; }
            float vp = vv[k] * ss[k];              // >= 0: sign bit free
            int b = r >> 5;
            int rib = (r & 31) | (half << 5);
            rec[k] = ((unsigned long long)__float_as_uint(vp) << 32)
                   | ((unsigned long long)(b >> 10) << 63)
                   | ((unsigned int)(b & 0x3FF) << 22)
                   | ((unsigned int)rib << 16)
                   | (unsigned int)cc[k];
            atomicAdd(&lcnt[b], 1);
        }
        if (have_tail) {
            int r = rt, half = 0;
            if (r >= MEDNUM) { r -= MEDNUM; half = 1; }
            float vp = vt * st;
            int b = r >> 5;
            int rib = (r & 31) | (half << 5);
            rtail = ((unsigned long long)__float_as_uint(vp) << 32)
                  | ((unsigned long long)(b >> 10) << 63)
                  | ((unsigned int)(b & 0x3FF) << 22)
                  | ((unsigned int)rib << 16)
                  | (unsigned int)ct;
            atomicAdd(&lcnt[b], 1);
        }
    }
    __syncthreads();

    // ---- exclusive scan over 1563 buckets (2 per thread, wave+block scan) ----
    int i0 = tid * 2;
    int c0 = 0, c1 = 0;
    if (i0 < NBUCK)     c0 = lcnt[i0];
    if (i0 + 1 < NBUCK) c1 = lcnt[i0 + 1];
    int s = c0 + c1;
    int x = s;
#pragma unroll
    for (int d = 1; d < 64; d <<= 1) {
        int t = __shfl_up(x, d, 64);
        if ((tid & 63) >= d) x += t;
    }
    int wave = tid >> 6, lane = tid & 63;
    if (lane == 63) wsum[wave] = x;
    __syncthreads();
    if (tid == 0) {
        int acc = 0;
#pragma unroll
        for (int w = 0; w < 16; w++) { int t = wsum[w]; wsum[w] = acc; acc += t; }
    }
    __syncthreads();
    int excl = wsum[wave] + x - s;

    // ---- reserve global slab space, init cursors (own cells only: no race) ----
    {
        int e = excl;
        if (i0 < NBUCK) {
            if (c0 > 0) gstart[i0] = atomicAdd(&gcur[i0], c0) - e;
            lcnt[i0] = e;
            e += c0;
        }
        if (i0 + 1 < NBUCK) {
            if (c1 > 0) gstart[i0 + 1] = atomicAdd(&gcur[i0 + 1], c1) - e;
            lcnt[i0 + 1] = e;
            e += c1;
        }
    }
    __syncthreads();

    // ---- place records into sorted LDS ----
#pragma unroll
    for (int k = 0; k < PART_K; k++) {
        unsigned long long r = rec[k];
        int b = (int)(((r >> 53) & 0x400u) | ((r >> 22) & 0x3FFu));
        int pos = atomicAdd(&lcnt[b], 1);
        lrec[pos] = r;
    }
    if (have_tail) {
        unsigned long long r = rtail;
        int b = (int)(((r >> 53) & 0x400u) | ((r >> 22) & 0x3FFu));
        int pos = atomicAdd(&lcnt[b], 1);
        lrec[pos] = r;
    }
    __syncthreads();

    // ---- position-ordered writeout: sequential runs per bucket (~64 B) ----
#pragma unroll
    for (int k = 0; k < PART_K; k++) {
        int j = k * PART_T + tid;
        unsigned long long r = lrec[j];
        int b = (int)(((r >> 53) & 0x400u) | ((r >> 22) & 0x3FFu));
        recs[gstart[b] + j] = r & 0x7FFFFFFFFFFFFFFFULL;   // clear bkt bit10
    }
    if (have_tail) {
        int j = PART_K * PART_T + tid;
        unsigned long long r = lrec[j];
        int b = (int)(((r >> 53) & 0x400u) | ((r >> 22) & 0x3FFu));
        recs[gstart[b] + j] = r & 0x7FFFFFFFFFFFFFFFULL;
    }
}

// ---------------------------------------------------------------------------
// 2) aggregate: one block per 32-row bucket, 256 THREADS (4 waves), grid 1563.
//    Round-12 analysis: 512-thr blocks capped at 4 blocks/CU (wave limit) ->
//    1024 concurrent blocks -> 1563/1024 = 1.53 scheduling rounds, second
//    round half-empty (measured 43% occupancy). 256-thr blocks + no slab8
//    LDS staging (hist + place passes read the slab straight from global;
//    pass 1 uses CACHED loads so the block's own 18 KB range is L2-hot for
//    pass 2) -> ~9.8 KB LDS -> 8 blocks/CU -> 2048 >= 1563: every block
//    resident, single round, 4-way block interleave hides gather latency.
//    Each wave now owns 8 folded rows (i2 0..7). Compute body unchanged
//    (40 VGPR measured) -> fits the (256,8) 64-VGPR cap, no spill.
// ---------------------------------------------------------------------------
__device__ __forceinline__ void accum8_body(const unsigned int p[8],
                                            const unsigned short* __restrict__ qt,
                                            unsigned int flo,
                                            float acc[8], float& sv) {
    unsigned long long w[8];
#pragma unroll
    for (int q = 0; q < 8; q++)
        w[q] = *(const unsigned long long*)((const char*)qt
                   + (((p[q] & 0xffffu) << 7) | flo));
#pragma unroll
    for (int q = 0; q < 8; q++) {
        float v = __uint_as_float(p[q] & 0xffff0000u);      // p==0 -> v=+0 -> no-op
        sv += v;
        unsigned int wlo = (unsigned int)w[q], whi = (unsigned int)(w[q] >> 32);
        acc[0] = fmaf(v, (float)(wlo & 0xffu),         acc[0]);
        acc[1] = fmaf(v, (float)((wlo >> 8) & 0xffu),  acc[1]);
        acc[2] = fmaf(v, (float)((wlo >> 16) & 0xffu), acc[2]);
        acc[3] = fmaf(v, (float)(wlo >> 24),           acc[3]);
        acc[4] = fmaf(v, (float)(whi & 0xffu),         acc[4]);
        acc[5] = fmaf(v, (float)((whi >> 8) & 0xffu),  acc[5]);
        acc[6] = fmaf(v, (float)((whi >> 16) & 0xffu), acc[6]);
        acc[7] = fmaf(v, (float)(whi >> 24),           acc[7]);
    }
}

// accumulate segment, reduce across quarters, select lane's 2 features,
// un-bias and relu -> only (rx, ry) live on exit.
__device__ __forceinline__ void seg_to_pair(int s, int e,
                                            const unsigned int* __restrict__ st4,
                                            const unsigned short* __restrict__ qt,
                                            int qw, unsigned int flo,
                                            float& rx, float& ry) {
    float acc[8], sv;
#pragma unroll
    for (int x = 0; x < 8; x++) acc[x] = 0.f;
    sv = 0.f;
    int i = s;
    for (; i + 32 <= e; i += 32) {                 // full chunks: no compares
        unsigned int p[8];
#pragma unroll
        for (int q = 0; q < 8; q++) p[q] = st4[i + q * 4 + qw];
        accum8_body(p, qt, flo, acc, sv);
    }
    if (i < e) {                                    // masked tail chunk
        unsigned int p[8];
#pragma unroll
        for (int q = 0; q < 8; q++) {
            int j = i + q * 4 + qw;
            p[q] = (j < e) ? st4[j] : 0u;   // p=0 -> v=0 -> contributes nothing
        }
        accum8_body(p, qt, flo, acc, sv);
    }
    // cross-quarter reduction: all lanes end with their quarter's full sums
#pragma unroll
    for (int x = 0; x < 8; x++) {
        acc[x] += __shfl_xor(acc[x], 16, 64);
        acc[x] += __shfl_xor(acc[x], 32, 64);
    }
    sv += __shfl_xor(sv, 16, 64);
    sv += __shfl_xor(sv, 32, 64);
    // lane l owns features 2l, 2l+1 = elements 2*qw, 2*qw+1 (permuted qt)
    float sx = (qw & 2) ? ((qw & 1) ? acc[6] : acc[4]) : ((qw & 1) ? acc[2] : acc[0]);
    float sy = (qw & 2) ? ((qw & 1) ? acc[7] : acc[5]) : ((qw & 1) ? acc[3] : acc[1]);
    rx = fmaxf(fmaf(-128.f, sv, sx), 0.f);   // un-bias + relu
    ry = fmaxf(fmaf(-128.f, sv, sy), 0.f);
}

__global__ __launch_bounds__(256, 8) void agg_kernel(const int* __restrict__ gcur,
                                                     const unsigned long long* __restrict__ recs,
                                                     const unsigned short* __restrict__ qt,
                                                     const float* __restrict__ inter,
                                                     float* __restrict__ out) {
    __shared__ unsigned int st4[CAP];           // 9216 B — sorted compressed recs
    __shared__ int cnt[64];
    __shared__ int bas[65];
    int b = blockIdx.x, tid = threadIdx.x;
    long long gs = (long long)b * SLAB;
    int n = gcur[b] - b * SLAB;
    if (n > CAP) n = CAP;   // slab overflow guard (P ~ 1e-5)

    if (tid < 64) cnt[tid] = 0;
    __syncthreads();
    // pass 1: histogram (CACHED loads -> slab range L2-hot for pass 2)
    for (int j = tid; j < n; j += 256) {
        unsigned long long r = recs[gs + j];
        atomicAdd(&cnt[(int)((r >> 16) & 63)], 1);
    }
    __syncthreads();
    // exclusive scan of 64 bins (single wave, shfl)
    if (tid < 64) {
        int v = cnt[tid];
        int x = v;
#pragma unroll
        for (int d = 1; d < 64; d <<= 1) {
            int tmp = __shfl_up(x, d, 64);
            if (tid >= d) x += tmp;
        }
        bas[tid] = x - v;
        if (tid == 63) bas[64] = x;
        cnt[tid] = x - v;          // cursor init
    }
    __syncthreads();
    // pass 2: place compressed records (re-read slab, L2-hot)
    for (int j = tid; j < n; j += 256) {
        unsigned long long r = recs[gs + j];
        int rib = (int)((r >> 16) & 63);
        int p = atomicAdd(&cnt[rib], 1);
        unsigned int vb = (unsigned int)(r >> 32);
        vb = (vb + 0x7fffu + ((vb >> 16) & 1u)) & 0xffff0000u;   // fp32->bf16 RNE
        st4[p] = ((unsigned int)(r & 0xffff)) | vb;
    }
    __syncthreads();
    // compute: wave w (0..3) handles folded rows b*32 + w*8 .. +7
    float t = inter[0];
    float s1 = 2.f * t, s2 = 2.f * (1.f - t);
    int wave = tid >> 6, lane = tid & 63;
    int qw = lane >> 4;                    // quarter-wave 0..3 (record slot)
    unsigned int flo = (unsigned int)((lane & 15) << 3);  // byte off in qt row
#pragma unroll 1
    for (int i2 = 0; i2 < 8; i2++) {
        int rib0 = wave * 8 + i2;          // 0..31
        int frow = b * 32 + rib0;
        if (frow >= MEDNUM) break;
        float ax, ay, cx, cy;
        seg_to_pair(bas[rib0],      bas[rib0 + 1],  st4, qt, qw, flo, ax, ay);  // half 0
        seg_to_pair(bas[rib0 + 32], bas[rib0 + 33], st4, qt, qw, flo, cx, cy);  // half 1
        float ox = s1 * ax + s2 * cx;
        float oy = s1 * ay + s2 * cy;
        unsigned long long packed =
            (unsigned long long)__float_as_uint(ox)
          | ((unsigned long long)__float_as_uint(oy) << 32);
        __builtin_nontemporal_store(packed,
            (unsigned long long*)(out + (long long)frow * FEATDIM + lane * 2));
    }
}

extern "C" void kernel_launch(void* const* d_in, const int* in_sizes, int n_in,
                              void* d_out, int out_size, void* d_ws, size_t ws_size,
                              hipStream_t stream) {
    const float* vals    = (const float*)d_in[0];
    const float* mEmbed  = (const float*)d_in[1];
    const float* inter   = (const float*)d_in[2];
    const int*   row_idx = (const int*)d_in[3];
    const int*   col_idx = (const int*)d_in[4];
    float* out = (float*)d_out;

    int* ws = (int*)d_ws;
    int* gcur = ws + OFF_CUR;
    float* scales = (float*)(ws + OFF_SCALE);
    unsigned short* qt = (unsigned short*)(ws + OFF_QT);
    unsigned long long* recs = (unsigned long long*)(ws + OFF_RECS);

    toint8_kernel<<<(MEDNUM + 3) / 4, 256, 0, stream>>>(mEmbed, qt, scales, gcur);
    part_kernel<<<PART_BLOCKS, PART_T, 0, stream>>>(vals, row_idx, col_idx, scales, gcur, recs);
    agg_kernel<<<NBUCK, 256, 0, stream>>>(gcur, recs, qt, inter, out);
}

// Round 14
// 196.649 us; speedup vs baseline: 1.1305x; 1.1305x over previous
//
#include <hip/hip_runtime.h>

#define MEDNUM 50000
#define FEATDIM 128
#define NNZ 3200000
#define NBUCK 1563             // ceil(50000/32): buckets of 32 folded rows
#define SLAB 2304              // fixed slab per bucket (mean 2047, +5.7 sigma)
#define PART_BLOCKS 250
#define PART_E 12800           // edges per block (250*12800 = NNZ exact)
#define PART_T 1024            // threads per part block (4 waves/SIMD)
#define PART_K 12              // 12*1024 = 12288 full records per thread
#define PART_TAIL 512          // 12800 - 12288
#define CAP SLAB

// ws layout (4-byte words):
#define OFF_CUR    0           // global slab cursors [1563]
#define OFF_SCALE  1600        // per-row fp32 scale [50000]
#define OFF_QT     51600       // biased-u8 table, PERMUTED layout, u16[50000*64] = 6.4 MB
#define OFF_RECS   3251600     // u64[NBUCK*SLAB] = 28.8 MB

// qt row layout (128 B): byte position 8q+j (q=0..15, j=0..7) holds feature
// 2q + 32*(j>>1) + (j&1). After agg's xor-16/32 reduction, lane l owns
// features 2l, 2l+1 (elements j=2*qw, 2*qw+1), so the output store is a dense
// 64-lane 8B store (512 B fully-covered lines -> no sector-RMW amplification).

// ---------------------------------------------------------------------------
// 0) fp32 -> per-row-scaled BIASED uint8 table (q+128; decode in agg uses
//    v_cvt_f32_ubyteN + deferred -128*sum(v) correction). One wave per row;
//    lane quantizes feats 2*lane, 2*lane+1 and stores the packed u16 at the
//    PERMUTED index (lane&15)*4 + (lane>>4). Also inits slab cursors.
// ---------------------------------------------------------------------------
__global__ __launch_bounds__(256) void toint8_kernel(const float* __restrict__ mEmbed,
                                                     unsigned short* __restrict__ qt,
                                                     float* __restrict__ scales,
                                                     int* __restrict__ gcur) {
    int g = blockIdx.x * 256 + threadIdx.x;
    if (g < NBUCK) gcur[g] = g * SLAB;

    int row = blockIdx.x * 4 + (threadIdx.x >> 6);
    int lane = threadIdx.x & 63;
    if (row >= MEDNUM) return;
    float2 f = ((const float2*)(mEmbed + (long long)row * FEATDIM))[lane];
    float m = fmaxf(fabsf(f.x), fabsf(f.y));
    for (int o = 32; o > 0; o >>= 1) m = fmaxf(m, __shfl_xor(m, o, 64));
    float inv = (m > 0.f) ? 127.f / m : 0.f;
    float s   = (m > 0.f) ? m / 127.f : 0.f;
    int q0 = __float2int_rn(f.x * inv) + 128;   // 1..255 biased
    int q1 = __float2int_rn(f.y * inv) + 128;
    qt[(long long)row * 64 + ((lane & 15) * 4 + (lane >> 4))] =
        (unsigned short)((q0 & 0xff) | ((q1 & 0xff) << 8));
    if (lane == 0) scales[row] = s;
}

// ---------------------------------------------------------------------------
// 1) partition: block-level counting sort. 250 blocks x 1024 threads, 12800
//    edges/block as u64 records in REGISTERS (K=12 + 512-thread tail), LDS
//    histogram -> block scan -> one global atomic per bucket -> place into
//    sorted LDS (102 KB) -> position-ordered coalesced writeout (~8-rec runs).
//    Record u64: [63]=bkt bit10 (vp sign is always 0; cleared on writeout),
//    [62:32]=vp fp32 bits (sign 0), [31:22]=bkt low10, [21:16]=rib, [15:0]=col.
// ---------------------------------------------------------------------------
__global__ __launch_bounds__(PART_T, 4) void part_kernel(const float* __restrict__ vals,
                                                         const int* __restrict__ row_idx,
                                                         const int* __restrict__ col_idx,
                                                         const float* __restrict__ scales,
                                                         int* __restrict__ gcur,
                                                         unsigned long long* __restrict__ recs) {
    __shared__ unsigned long long lrec[PART_E];   // 102400 B
    __shared__ int lcnt[NBUCK];                   // counts -> cursors
    __shared__ int gstart[NBUCK];                 // global_base - local_excl per bucket
    __shared__ int wsum[16];

    int tid = threadIdx.x;
    int base = blockIdx.x * PART_E;

    for (int i = tid; i < NBUCK; i += PART_T) lcnt[i] = 0;
    __syncthreads();

    // ---- single input pass: build records in registers + LDS histogram ----
    unsigned long long rec[PART_K];
    unsigned long long rtail = 0;
    int have_tail = (tid < PART_TAIL);
    {
        int rr[PART_K], cc[PART_K];
        float vv[PART_K];
#pragma unroll
        for (int k = 0; k < PART_K; k++) {
            int e = base + k * PART_T + tid;
            rr[k] = __builtin_nontemporal_load(row_idx + e);
            cc[k] = __builtin_nontemporal_load(col_idx + e);
            vv[k] = __builtin_nontemporal_load(vals + e);
        }
        int rt = 0, ct = 0; float vt = 0.f;
        if (have_tail) {
            int e = base + PART_K * PART_T + tid;
            rt = __builtin_nontemporal_load(row_idx + e);
            ct = __builtin_nontemporal_load(col_idx + e);
            vt = __builtin_nontemporal_load(vals + e);
        }
        float ss[PART_K];
#pragma unroll
        for (int k = 0; k < PART_K; k++) {
            cc[k] = (cc[k] >= MEDNUM) ? cc[k] - MEDNUM : cc[k];
            ss[k] = scales[cc[k]];
        }
        float st = 0.f;
        if (have_tail) {
            ct = (ct >= MEDNUM) ? ct - MEDNUM : ct;
            st = scales[ct];
        }
#pragma unroll
        for (int k = 0; k < PART_K; k++) {
            int r = rr[k], half = 0;
            if (r >= MEDNUM) { r -= MEDNUM; half = 1; }
            float vp = vv[k] * ss[k];              // >= 0: sign bit free
            int b = r >> 5;
            int rib = (r & 31) | (half << 5);
            rec[k] = ((unsigned long long)__float_as_uint(vp) << 32)
                   | ((unsigned long long)(b >> 10) << 63)
                   | ((unsigned int)(b & 0x3FF) << 22)
                   | ((unsigned int)rib << 16)
                   | (unsigned int)cc[k];
            atomicAdd(&lcnt[b], 1);
        }
        if (have_tail) {
            int r = rt, half = 0;
            if (r >= MEDNUM) { r -= MEDNUM; half = 1; }
            float vp = vt * st;
            int b = r >> 5;
            int rib = (r & 31) | (half << 5);
            rtail = ((unsigned long long)__float_as_uint(vp) << 32)
                  | ((unsigned long long)(b >> 10) << 63)
                  | ((unsigned int)(b & 0x3FF) << 22)
                  | ((unsigned int)rib << 16)
                  | (unsigned int)ct;
            atomicAdd(&lcnt[b], 1);
        }
    }
    __syncthreads();

    // ---- exclusive scan over 1563 buckets (2 per thread, wave+block scan) ----
    int i0 = tid * 2;
    int c0 = 0, c1 = 0;
    if (i0 < NBUCK)     c0 = lcnt[i0];
    if (i0 + 1 < NBUCK) c1 = lcnt[i0 + 1];
    int s = c0 + c1;
    int x = s;
#pragma unroll
    for (int d = 1; d < 64; d <<= 1) {
        int t = __shfl_up(x, d, 64);
        if ((tid & 63) >= d) x += t;
    }
    int wave = tid >> 6, lane = tid & 63;
    if (lane == 63) wsum[wave] = x;
    __syncthreads();
    if (tid == 0) {
        int acc = 0;
#pragma unroll
        for (int w = 0; w < 16; w++) { int t = wsum[w]; wsum[w] = acc; acc += t; }
    }
    __syncthreads();
    int excl = wsum[wave] + x - s;

    // ---- reserve global slab space, init cursors (own cells only: no race) ----
    {
        int e = excl;
        if (i0 < NBUCK) {
            if (c0 > 0) gstart[i0] = atomicAdd(&gcur[i0], c0) - e;
            lcnt[i0] = e;
            e += c0;
        }
        if (i0 + 1 < NBUCK) {
            if (c1 > 0) gstart[i0 + 1] = atomicAdd(&gcur[i0 + 1], c1) - e;
            lcnt[i0 + 1] = e;
            e += c1;
        }
    }
    __syncthreads();

    // ---- place records into sorted LDS ----
#pragma unroll
    for (int k = 0; k < PART_K; k++) {
        unsigned long long r = rec[k];
        int b = (int)(((r >> 53) & 0x400u) | ((r >> 22) & 0x3FFu));
        int pos = atomicAdd(&lcnt[b], 1);
        lrec[pos] = r;
    }
    if (have_tail) {
        unsigned long long r = rtail;
        int b = (int)(((r >> 53) & 0x400u) | ((r >> 22) & 0x3FFu));
        int pos = atomicAdd(&lcnt[b], 1);
        lrec[pos] = r;
    }
    __syncthreads();

    // ---- position-ordered writeout: sequential runs per bucket (~64 B) ----
#pragma unroll
    for (int k = 0; k < PART_K; k++) {
        int j = k * PART_T + tid;
        unsigned long long r = lrec[j];
        int b = (int)(((r >> 53) & 0x400u) | ((r >> 22) & 0x3FFu));
        recs[gstart[b] + j] = r & 0x7FFFFFFFFFFFFFFFULL;   // clear bkt bit10
    }
    if (have_tail) {
        int j = PART_K * PART_T + tid;
        unsigned long long r = lrec[j];
        int b = (int)(((r >> 53) & 0x400u) | ((r >> 22) & 0x3FFu));
        recs[gstart[b] + j] = r & 0x7FFFFFFFFFFFFFFFULL;
    }
}

// ---------------------------------------------------------------------------
// 2) aggregate: one block per 32-row bucket (grid 1563, 512 threads).
//    LDS-MINIMAL prologue: the slab is staged in REGISTERS (rl[5], 10 VGPR)
//    across the hist/scan/place barriers — single global read like round 12,
//    but LDS drops 28.2 -> 9.7 KB (slab8 deleted). Occupancy correlated
//    inversely with LDS across rounds (10 KB -> 64%, 28.7 KB -> 44%); this
//    buys back block residency. Spill-safe: (512,6) = 85-reg cap, body
//    measured 40 VGPR + 10 staging (round 2's spill was the same staging
//    under (512,8)'s 64-reg cap). WRITE_SIZE is the tripwire: 25.0 MB clean,
//    more = spill. Compute body identical to round 12.
// ---------------------------------------------------------------------------
__device__ __forceinline__ void accum8_body(const unsigned int p[8],
                                            const unsigned short* __restrict__ qt,
                                            unsigned int flo,
                                            float acc[8], float& sv) {
    unsigned long long w[8];
#pragma unroll
    for (int q = 0; q < 8; q++)
        w[q] = *(const unsigned long long*)((const char*)qt
                   + (((p[q] & 0xffffu) << 7) | flo));
#pragma unroll
    for (int q = 0; q < 8; q++) {
        float v = __uint_as_float(p[q] & 0xffff0000u);      // p==0 -> v=+0 -> no-op
        sv += v;
        unsigned int wlo = (unsigned int)w[q], whi = (unsigned int)(w[q] >> 32);
        acc[0] = fmaf(v, (float)(wlo & 0xffu),         acc[0]);
        acc[1] = fmaf(v, (float)((wlo >> 8) & 0xffu),  acc[1]);
        acc[2] = fmaf(v, (float)((wlo >> 16) & 0xffu), acc[2]);
        acc[3] = fmaf(v, (float)(wlo >> 24),           acc[3]);
        acc[4] = fmaf(v, (float)(whi & 0xffu),         acc[4]);
        acc[5] = fmaf(v, (float)((whi >> 8) & 0xffu),  acc[5]);
        acc[6] = fmaf(v, (float)((whi >> 16) & 0xffu), acc[6]);
        acc[7] = fmaf(v, (float)(whi >> 24),           acc[7]);
    }
}

// accumulate segment, reduce across quarters, select lane's 2 features,
// un-bias and relu -> only (rx, ry) live on exit.
__device__ __forceinline__ void seg_to_pair(int s, int e,
                                            const unsigned int* __restrict__ st4,
                                            const unsigned short* __restrict__ qt,
                                            int qw, unsigned int flo,
                                            float& rx, float& ry) {
    float acc[8], sv;
#pragma unroll
    for (int x = 0; x < 8; x++) acc[x] = 0.f;
    sv = 0.f;
    int i = s;
    for (; i + 32 <= e; i += 32) {                 // full chunks: no compares
        unsigned int p[8];
#pragma unroll
        for (int q = 0; q < 8; q++) p[q] = st4[i + q * 4 + qw];
        accum8_body(p, qt, flo, acc, sv);
    }
    if (i < e) {                                    // masked tail chunk
        unsigned int p[8];
#pragma unroll
        for (int q = 0; q < 8; q++) {
            int j = i + q * 4 + qw;
            p[q] = (j < e) ? st4[j] : 0u;   // p=0 -> v=0 -> contributes nothing
        }
        accum8_body(p, qt, flo, acc, sv);
    }
    // cross-quarter reduction: all lanes end with their quarter's full sums
#pragma unroll
    for (int x = 0; x < 8; x++) {
        acc[x] += __shfl_xor(acc[x], 16, 64);
        acc[x] += __shfl_xor(acc[x], 32, 64);
    }
    sv += __shfl_xor(sv, 16, 64);
    sv += __shfl_xor(sv, 32, 64);
    // lane l owns features 2l, 2l+1 = elements 2*qw, 2*qw+1 (permuted qt)
    float sx = (qw & 2) ? ((qw & 1) ? acc[6] : acc[4]) : ((qw & 1) ? acc[2] : acc[0]);
    float sy = (qw & 2) ? ((qw & 1) ? acc[7] : acc[5]) : ((qw & 1) ? acc[3] : acc[1]);
    rx = fmaxf(fmaf(-128.f, sv, sx), 0.f);   // un-bias + relu
    ry = fmaxf(fmaf(-128.f, sv, sy), 0.f);
}

__global__ __launch_bounds__(512, 6) void agg_kernel(const int* __restrict__ gcur,
                                                     const unsigned long long* __restrict__ recs,
                                                     const unsigned short* __restrict__ qt,
                                                     const float* __restrict__ inter,
                                                     float* __restrict__ out) {
    __shared__ unsigned int st4[CAP];           // 9216 B — sorted compressed recs
    __shared__ int cnt[64];
    __shared__ int bas[65];
    int b = blockIdx.x, tid = threadIdx.x;
    long long gs = (long long)b * SLAB;
    int n = gcur[b] - b * SLAB;
    if (n > CAP) n = CAP;   // slab overflow guard (P ~ 1e-5)

    if (tid < 64) cnt[tid] = 0;
    __syncthreads();
    // stage slab into REGISTERS (single global read) with fused histogram
    unsigned long long rl[5];
#pragma unroll
    for (int k = 0; k < 5; k++) {
        int j = k * 512 + tid;
        if (j < n) {
            rl[k] = __builtin_nontemporal_load(recs + gs + j);
            atomicAdd(&cnt[(int)((rl[k] >> 16) & 63)], 1);
        }
    }
    __syncthreads();
    // exclusive scan of 64 bins (single wave, shfl)
    if (tid < 64) {
        int v = cnt[tid];
        int x = v;
#pragma unroll
        for (int d = 1; d < 64; d <<= 1) {
            int tmp = __shfl_up(x, d, 64);
            if (tid >= d) x += tmp;
        }
        bas[tid] = x - v;
        if (tid == 63) bas[64] = x;
        cnt[tid] = x - v;          // cursor init
    }
    __syncthreads();
    // place compressed records from registers
#pragma unroll
    for (int k = 0; k < 5; k++) {
        int j = k * 512 + tid;
        if (j < n) {
            unsigned long long r = rl[k];
            int rib = (int)((r >> 16) & 63);
            int p = atomicAdd(&cnt[rib], 1);
            unsigned int vb = (unsigned int)(r >> 32);
            vb = (vb + 0x7fffu + ((vb >> 16) & 1u)) & 0xffff0000u;   // fp32->bf16 RNE
            st4[p] = ((unsigned int)(r & 0xffff)) | vb;
        }
    }
    __syncthreads();
    // compute: wave w handles folded rows b*32 + w*4 .. +3
    float t = inter[0];
    float s1 = 2.f * t, s2 = 2.f * (1.f - t);
    int wave = tid >> 6, lane = tid & 63;
    int qw = lane >> 4;                    // quarter-wave 0..3 (record slot)
    unsigned int flo = (unsigned int)((lane & 15) << 3);  // byte off in qt row
#pragma unroll 1
    for (int i2 = 0; i2 < 4; i2++) {
        int rib0 = wave * 4 + i2;          // 0..31
        int frow = b * 32 + rib0;
        if (frow >= MEDNUM) break;
        float ax, ay, cx, cy;
        seg_to_pair(bas[rib0],      bas[rib0 + 1],  st4, qt, qw, flo, ax, ay);  // half 0
        seg_to_pair(bas[rib0 + 32], bas[rib0 + 33], st4, qt, qw, flo, cx, cy);  // half 1
        float ox = s1 * ax + s2 * cx;
        float oy = s1 * ay + s2 * cy;
        unsigned long long packed =
            (unsigned long long)__float_as_uint(ox)
          | ((unsigned long long)__float_as_uint(oy) << 32);
        __builtin_nontemporal_store(packed,
            (unsigned long long*)(out + (long long)frow * FEATDIM + lane * 2));
    }
}

extern "C" void kernel_launch(void* const* d_in, const int* in_sizes, int n_in,
                              void* d_out, int out_size, void* d_ws, size_t ws_size,
                              hipStream_t stream) {
    const float* vals    = (const float*)d_in[0];
    const float* mEmbed  = (const float*)d_in[1];
    const float* inter   = (const float*)d_in[2];
    const int*   row_idx = (const int*)d_in[3];
    const int*   col_idx = (const int*)d_in[4];
    float* out = (float*)d_out;

    int* ws = (int*)d_ws;
    int* gcur = ws + OFF_CUR;
    float* scales = (float*)(ws + OFF_SCALE);
    unsigned short* qt = (unsigned short*)(ws + OFF_QT);
    unsigned long long* recs = (unsigned long long*)(ws + OFF_RECS);

    toint8_kernel<<<(MEDNUM + 3) / 4, 256, 0, stream>>>(mEmbed, qt, scales, gcur);
    part_kernel<<<PART_BLOCKS, PART_T, 0, stream>>>(vals, row_idx, col_idx, scales, gcur, recs);
    agg_kernel<<<NBUCK, 512, 0, stream>>>(gcur, recs, qt, inter, out);
}